// Round 4
// baseline (1525.804 us; speedup 1.0000x reference)
//
#include <hip/hip_runtime.h>

// ---------------- problem constants ----------------
#define D_SZ 512
#define S_SZ 1024
#define H_SZ 2048
#define BS_SZ 32768
#define H_STEP 0.1f

typedef __attribute__((ext_vector_type(4))) float f32x4;
typedef __attribute__((ext_vector_type(8))) short s16x8;
typedef __attribute__((ext_vector_type(4))) unsigned short u16x4;
typedef unsigned short ushort_t;

__device__ __forceinline__ ushort_t f2b(float f) {
    unsigned u = __float_as_uint(f);
    unsigned r = (u + 0x7FFFu + ((u >> 16) & 1u)) >> 16;
    return (ushort_t)r;
}

__device__ __forceinline__ void gload_lds16(const void* g, void* l) {
    __builtin_amdgcn_global_load_lds(
        (const __attribute__((address_space(1))) unsigned int*)g,
        (__attribute__((address_space(3))) unsigned int*)l, 16, 0, 0);
}

// ---------------- prep kernels ----------------
__global__ void prep_w1(const float* __restrict__ W1,
                        ushort_t* __restrict__ W1b,
                        ushort_t* __restrict__ W1T) {
    int idx = blockIdx.x * 256 + threadIdx.x;   // over H*D = 1M
    float v = W1[idx];
    ushort_t b = f2b(v);
    int h = idx >> 9;          // / 512
    int d = idx & 511;
    W1b[idx] = b;
    W1T[(size_t)d * H_SZ + h] = b;
}

__global__ void prep_mass(const float* __restrict__ logm,
                          float* __restrict__ inv_mass,
                          float* __restrict__ mass) {
    int s = blockIdx.x * 256 + threadIdx.x;
    if (s < S_SZ) {
        float lm = logm[s];
        mass[s] = expf(lm);
        inv_mass[s] = expf(-lm);
    }
}

// ---------------- embedding + p0 ----------------
__global__ void embed_kernel(const float* __restrict__ table,
                             const int* __restrict__ ids,
                             const float* __restrict__ mass,
                             float* __restrict__ q,
                             float* __restrict__ p,
                             ushort_t* __restrict__ qb) {
    int i = blockIdx.x;          // row index in [0, BS)
    int t = threadIdx.x;
    int s = i & (S_SZ - 1);
    int id = ids[i];
    int idp = (s == 0) ? id : ids[i - 1];   // s==0: prev = self -> vel 0
    float mk = (id != 0) ? 1.f : 0.f;
    float ms = mass[s];
    int d0 = t * 4;

    f32x4 cur = {0.f, 0.f, 0.f, 0.f};
    f32x4 prv = {0.f, 0.f, 0.f, 0.f};
    if (id != 0)  cur = *(const f32x4*)(table + (size_t)id  * D_SZ + d0);
    if (idp != 0) prv = *(const f32x4*)(table + (size_t)idp * D_SZ + d0);

    size_t off = (size_t)i * D_SZ + d0;
    *(f32x4*)(q + off) = cur;
    u16x4 cb;
    cb[0] = f2b(cur[0]); cb[1] = f2b(cur[1]); cb[2] = f2b(cur[2]); cb[3] = f2b(cur[3]);
    *(u16x4*)(qb + off) = cb;

    f32x4 pv;
    pv[0] = ms * (cur[0] - prv[0]) * mk;
    pv[1] = ms * (cur[1] - prv[1]) * mk;
    pv[2] = ms * (cur[2] - prv[2]) * mk;
    pv[3] = ms * (cur[3] - prv[3]) * mk;
    *(f32x4*)(p + off) = pv;
}

// =====================================================================
// Phased 128x256 GEMM core, BK=32, 2 LDS buffers (48 KB -> 2 blocks/CU),
// counted vmcnt(3), T2 XOR-swizzle (pre-swizzled global source),
// T5 setprio, bijective XCD swizzle. 8 waves (2x4), per-wave 64x64.
// C[r][c] = sum_k A[r,k]*B[c,k];  A rows = MAB*128, B rows = 32768.
// EPI 0: force1 (U store); EPI 1: force2 (p/q leapfrog update).
// =====================================================================
template<int KLEN, int MAB, int EPI>
__global__ __launch_bounds__(512, 4) void gemm8(
        const ushort_t* __restrict__ A,
        const ushort_t* __restrict__ B,
        const float* __restrict__ b1,
        const float* __restrict__ W2,
        ushort_t* __restrict__ U,
        const int* __restrict__ ids,
        const float* __restrict__ inv_mass,
        float* __restrict__ q,
        float* __restrict__ p,
        ushort_t* __restrict__ qb,
        float coef, int do_q) {
    constexpr int NT = KLEN / 32;
    __shared__ __align__(16) ushort_t lA[2][128 * 32];   // 16 KB
    __shared__ __align__(16) ushort_t lB[2][256 * 32];   // 32 KB

    const int tid = threadIdx.x;
    const int lane = tid & 63, wid = tid >> 6;
    const int wm = wid >> 2, wn = wid & 3;           // 2 x 4 wave grid
    const int lr = lane & 15, lk = lane >> 4;

    // bijective XCD swizzle (nwg % 8 == 0); A-blocks fastest (share B i-tile)
    const int nwg = MAB * 128;
    int wgid = ((int)blockIdx.x & 7) * (nwg >> 3) + ((int)blockIdx.x >> 3);
    int bxA = wgid % MAB;
    int by  = wgid / MAB;
    const long a0 = (long)bxA * 128;
    const long b0 = (long)by * 256;

    // ---- staging: A = 512 chunks (1/thread), B = 1024 chunks (2/thread)
    // chunk -> row r=tid>>2, 16B-slot kc=tid&3; swizzled source slot kc^((r>>1)&3)
    const int rr  = tid >> 2;                 // 0..127
    const int kc  = tid & 3;
    const int kcs = kc ^ ((rr >> 1) & 3);     // same for row rr+128 (128>>1 & 3 == 0)
    const ushort_t* gA  = A + (a0 + rr) * (long)KLEN + kcs * 8;
    const ushort_t* gB1 = B + (b0 + rr) * (long)KLEN + kcs * 8;
    const ushort_t* gB2 = gB1 + (long)128 * KLEN;
    const int ldA  = tid * 8;
    const int ldB1 = tid * 8;
    const int ldB2 = (tid + 512) * 8;

#define STAGE(t) { int _b = (t) & 1;                           \
    gload_lds16(gA  + (long)(t) * 32, &lA[_b][ldA]);           \
    gload_lds16(gB1 + (long)(t) * 32, &lB[_b][ldB1]);          \
    gload_lds16(gB2 + (long)(t) * 32, &lB[_b][ldB2]); }

    f32x4 acc[4][4];
    #pragma unroll
    for (int m = 0; m < 4; ++m)
        #pragma unroll
        for (int n = 0; n < 4; ++n)
            acc[m][n] = (f32x4){0.f, 0.f, 0.f, 0.f};

    // ds_read fragment offsets (ushort units), swizzled slot lk^((lr>>1)&3)
    const int lks8 = (lk ^ ((lr >> 1) & 3)) * 8;
    const int roA = (wm * 64 + lr) * 32 + lks8;   // + m*512 per 16-row frag
    const int roB = (wn * 64 + lr) * 32 + lks8;   // + n*512

    // prologue: tiles 0 and 1 staged (6 loads/thread in flight)
    STAGE(0);
    STAGE(1);

    for (int t = 0; t < NT; ++t) {
        const int buf = t & 1;
        const ushort_t* bA = &lA[buf][0];
        const ushort_t* bB = &lB[buf][0];
        // require tile t staged; keep tile t+1's 3 loads in flight
        if (t < NT - 1) asm volatile("s_waitcnt vmcnt(3)" ::: "memory");
        else           asm volatile("s_waitcnt vmcnt(0)" ::: "memory");
        __builtin_amdgcn_s_barrier();

        s16x8 av[4], bv[4];
        #pragma unroll
        for (int m = 0; m < 4; ++m) av[m] = *(const s16x8*)&bA[roA + m * 512];
        #pragma unroll
        for (int n = 0; n < 4; ++n) bv[n] = *(const s16x8*)&bB[roB + n * 512];
        __builtin_amdgcn_s_setprio(1);
        #pragma unroll
        for (int m = 0; m < 4; ++m)
            #pragma unroll
            for (int n = 0; n < 4; ++n)
                acc[m][n] = __builtin_amdgcn_mfma_f32_16x16x32_bf16(av[m], bv[n], acc[m][n], 0, 0, 0);
        __builtin_amdgcn_s_setprio(0);
        __builtin_amdgcn_s_barrier();          // all waves done reading buf t
        if (t + 2 < NT) STAGE(t + 2);          // overwrite buf t safely
    }
#undef STAGE

    if constexpr (EPI == 0) {
        // U[i,h] = bf16(sech2(C + b1[h]) * w2[h]); reg axis = h (contiguous)
        #pragma unroll
        for (int m = 0; m < 4; ++m) {
            long h0 = a0 + wm * 64 + m * 16 + lk * 4;
            f32x4 b1v = *(const f32x4*)(b1 + h0);
            f32x4 w2v = *(const f32x4*)(W2 + h0);
            #pragma unroll
            for (int n = 0; n < 4; ++n) {
                long i = b0 + wn * 64 + n * 16 + lr;
                u16x4 ub;
                #pragma unroll
                for (int j = 0; j < 4; ++j) {
                    float uu = acc[m][n][j] + b1v[j];
                    // sech^2(u) = 4e/(1+e)^2, e = exp(-2|u|)
                    float e = __expf(-2.0f * fabsf(uu));
                    float rc = 1.0f / (1.0f + e);
                    ub[j] = f2b(4.0f * e * rc * rc * w2v[j]);
                }
                *(u16x4*)(U + i * H_SZ + h0) = ub;
            }
        }
    } else {
        // p -= coef*mask*G ; q += 0.1*p/mass*mask ; qb = bf16(q). reg axis = d.
        #pragma unroll
        for (int n = 0; n < 4; ++n) {
            long i = b0 + wn * 64 + n * 16 + lr;
            int id = ids[i];
            float cm = (id != 0) ? coef : 0.f;
            float hm = (id != 0) ? H_STEP : 0.f;
            float im = inv_mass[(int)(i & (S_SZ - 1))];
            #pragma unroll
            for (int m = 0; m < 4; ++m) {
                long d0 = a0 + wm * 64 + m * 16 + lk * 4;
                size_t off = (size_t)i * D_SZ + d0;
                f32x4 pv = *(const f32x4*)(p + off);
                #pragma unroll
                for (int j = 0; j < 4; ++j)
                    pv[j] -= cm * acc[m][n][j];
                *(f32x4*)(p + off) = pv;
                if (do_q) {
                    f32x4 qv = *(const f32x4*)(q + off);
                    u16x4 qbv;
                    #pragma unroll
                    for (int j = 0; j < 4; ++j) {
                        qv[j] += hm * pv[j] * im;
                        qbv[j] = f2b(qv[j]);
                    }
                    *(f32x4*)(q + off) = qv;
                    *(u16x4*)(qb + off) = qbv;
                }
            }
        }
    }
}

// ---------------- host launch ----------------
extern "C" void kernel_launch(void* const* d_in, const int* in_sizes, int n_in,
                              void* d_out, int out_size, void* d_ws, size_t ws_size,
                              hipStream_t stream) {
    const float* table = (const float*)d_in[0];
    const float* logm  = (const float*)d_in[1];
    const float* W1    = (const float*)d_in[2];
    const float* b1    = (const float*)d_in[3];
    const float* W2    = (const float*)d_in[4];
    // d_in[5] = b2, unused by the force (only shifts the potential value)
    const int*   ids   = (const int*)d_in[6];

    float* q = (float*)d_out;                       // [BS, D]
    float* p = q + (size_t)BS_SZ * D_SZ;            // [BS, D]

    char* ws = (char*)d_ws;
    size_t o = 0;
    ushort_t* qb  = (ushort_t*)(ws + o); o += (size_t)BS_SZ * D_SZ * 2;   // 32 MB
    ushort_t* U   = (ushort_t*)(ws + o); o += (size_t)BS_SZ * H_SZ * 2;   // 128 MB
    ushort_t* W1b = (ushort_t*)(ws + o); o += (size_t)H_SZ * D_SZ * 2;    // 2 MB
    ushort_t* W1T = (ushort_t*)(ws + o); o += (size_t)D_SZ * H_SZ * 2;    // 2 MB
    float* inv_mass = (float*)(ws + o);  o += S_SZ * 4;
    float* mass     = (float*)(ws + o);  o += S_SZ * 4;

    prep_w1<<<(H_SZ * D_SZ) / 256, 256, 0, stream>>>(W1, W1b, W1T);
    prep_mass<<<(S_SZ + 255) / 256, 256, 0, stream>>>(logm, inv_mass, mass);
    embed_kernel<<<BS_SZ, 128, 0, stream>>>(table, ids, mass, q, p, qb);

    // 6 distinct force evals: j=0 -> +0.05*f(q0); j=1..4 -> +0.1*f(qj); j=5 -> +0.05*f(q5)
    for (int j = 0; j < 6; ++j) {
        // force1: A = W1b [2048 rows], B = qb [32768 rows], K=512 -> grid 16*128
        gemm8<512, 16, 0><<<2048, 512, 0, stream>>>(
            W1b, qb, b1, W2, U, nullptr, nullptr, nullptr, nullptr, nullptr, 0.f, 0);
        float coef = (j == 0 || j == 5) ? 0.05f : 0.1f;
        // force2: A = W1T [512 rows], B = U [32768 rows], K=2048 -> grid 4*128
        gemm8<2048, 4, 1><<<512, 512, 0, stream>>>(
            W1T, U, nullptr, nullptr, nullptr, ids, inv_mass, q, p, qb, coef, (j < 5) ? 1 : 0);
    }
}